// Round 6
// baseline (181.112 us; speedup 1.0000x reference)
//
#include <hip/hip_runtime.h>
#include <hip/hip_bf16.h>
#include <math.h>

#define D 128
#define NB2 96            // blocks per path in k_fc5
#define NWAVES (NB2 * 4)  // waves per path

typedef __attribute__((ext_vector_type(8))) short bf16x8;
typedef __attribute__((ext_vector_type(4))) float f32x4;

__device__ __forceinline__ float wave_sum(float v) {
#pragma unroll
  for (int off = 32; off; off >>= 1) v += __shfl_xor(v, off, 64);
  return v;
}

// fp32 -> bf16 round-to-nearest-even (finite inputs)
__device__ __forceinline__ unsigned bfr(float f) {
  const unsigned u = __float_as_uint(f);
  return (u + 0x7FFFu + ((u >> 16) & 1u)) >> 16;
}

// ---------------- Kernel P0: projections q = h_ref@a_ref, p = h@a_nei ----------------
// One wave per row. Rows [0,N): h_ref -> q1,q2. [N,N+M): h1 -> p1. [N+M,N+2M): h2 -> p2.
__global__ __launch_bounds__(256) void k_proj(
    const float* __restrict__ h_ref, const float* __restrict__ h1,
    const float* __restrict__ h2,
    const float* __restrict__ att1, const float* __restrict__ att2,
    float* __restrict__ q1, float* __restrict__ q2,
    float* __restrict__ p1, float* __restrict__ p2, int N, int M)
{
  const int lane = threadIdx.x & 63;
  const int r = blockIdx.x * 4 + (threadIdx.x >> 6);
  const int total = N + 2 * M;
  if (r >= total) return;
  if (r < N) {
    const float2 v  = *(const float2*)(h_ref + (size_t)r * D + 2 * lane);
    const float2 a1 = *(const float2*)(att1 + 2 * lane);
    const float2 a2 = *(const float2*)(att2 + 2 * lane);
    const float s1 = wave_sum(v.x * a1.x + v.y * a1.y);
    const float s2 = wave_sum(v.x * a2.x + v.y * a2.y);
    if (lane == 0) { q1[r] = s1; q2[r] = s2; }
  } else if (r < N + M) {
    const int m = r - N;
    const float2 v = *(const float2*)(h1 + (size_t)m * D + 2 * lane);
    const float2 a = *(const float2*)(att1 + D + 2 * lane);
    const float s = wave_sum(v.x * a.x + v.y * a.y);
    if (lane == 0) p1[m] = s;
  } else {
    const int m = r - N - M;
    const float2 v = *(const float2*)(h2 + (size_t)m * D + 2 * lane);
    const float2 a = *(const float2*)(att2 + D + 2 * lane);
    const float s = wave_sum(v.x * a.x + v.y * a.y);
    if (lane == 0) p2[m] = s;
  }
}

// ---------------- Kernel A (v2): intra attention via precomputed q/p ----------------
// One wave per node. Lane s<S gathers scalar p[nei_s]; softmax across lanes; row
// gathers are coalesced 512B; weights/rows broadcast via readlane (__shfl const).
template<int S>
__global__ __launch_bounds__(256) void k_intra2(
    const float* __restrict__ q, const float* __restrict__ p,
    const float* __restrict__ h, const int* __restrict__ nei,
    unsigned* __restrict__ eb, int N)
{
  const int lane = threadIdx.x & 63;
  const int n = blockIdx.x * 4 + (threadIdx.x >> 6);
  if (n >= N) return;

  const int myidx = (lane < S) ? nei[(size_t)n * S + lane] : 0;
  const float pv = (lane < S) ? p[myidx] : 0.f;
  float x = q[n] + pv;
  x = x > 0.f ? x : 0.01f * x;          // leaky_relu
  if (lane >= S) x = -1e30f;
  float m = x;
#pragma unroll
  for (int off = 32; off; off >>= 1) m = fmaxf(m, __shfl_xor(m, off, 64));
  const float ex = (lane < S) ? __expf(x - m) : 0.f;
  float sum = ex;
#pragma unroll
  for (int off = 32; off; off >>= 1) sum += __shfl_xor(sum, off, 64);
  const float w = ex / sum;             // lane s holds w_s

  float2 vv[S];
#pragma unroll
  for (int s = 0; s < S; ++s) {
    const int row = __shfl(myidx, s, 64);  // readlane: uniform row index
    vv[s] = *(const float2*)(h + (size_t)row * D + 2 * lane);
  }
  float ax0 = 0.f, ay0 = 0.f, ax1 = 0.f, ay1 = 0.f;
#pragma unroll
  for (int s = 0; s < S; s += 2) {       // S even (10/20)
    const float w0 = __shfl(w, s, 64);
    const float w1 = __shfl(w, s + 1, 64);
    ax0 = fmaf(w0, vv[s].x, ax0);     ay0 = fmaf(w0, vv[s].y, ay0);
    ax1 = fmaf(w1, vv[s + 1].x, ax1); ay1 = fmaf(w1, vv[s + 1].y, ay1);
  }
  float ex2 = ax0 + ax1, ey2 = ay0 + ay1;
  ex2 = ex2 > 0.f ? ex2 : expm1f(ex2);  // ELU
  ey2 = ey2 > 0.f ? ey2 : expm1f(ey2);
  eb[(size_t)n * (D / 2) + lane] = (bfr(ey2) << 16) | bfr(ex2);
}

// Generic fallback (runtime S, S <= 64)
__global__ __launch_bounds__(256) void k_intra2_gen(
    const float* __restrict__ q, const float* __restrict__ p,
    const float* __restrict__ h, const int* __restrict__ nei,
    unsigned* __restrict__ eb, int N, int S)
{
  const int lane = threadIdx.x & 63;
  const int n = blockIdx.x * 4 + (threadIdx.x >> 6);
  if (n >= N) return;
  const int myidx = (lane < S) ? nei[(size_t)n * S + lane] : 0;
  const float pv = (lane < S) ? p[myidx] : 0.f;
  float x = q[n] + pv;
  x = x > 0.f ? x : 0.01f * x;
  if (lane >= S) x = -1e30f;
  float m = x;
#pragma unroll
  for (int off = 32; off; off >>= 1) m = fmaxf(m, __shfl_xor(m, off, 64));
  const float ex = (lane < S) ? __expf(x - m) : 0.f;
  float sum = ex;
#pragma unroll
  for (int off = 32; off; off >>= 1) sum += __shfl_xor(sum, off, 64);
  const float w = ex / sum;
  float ax = 0.f, ay = 0.f;
  for (int s = 0; s < S; ++s) {
    const int row = __shfl(myidx, s, 64);
    const float ws = __shfl(w, s, 64);
    const float2 v = *(const float2*)(h + (size_t)row * D + 2 * lane);
    ax = fmaf(ws, v.x, ax);
    ay = fmaf(ws, v.y, ay);
  }
  ax = ax > 0.f ? ax : expm1f(ax);
  ay = ay > 0.f ? ay : expm1f(ay);
  eb[(size_t)n * (D / 2) + lane] = (bfr(ay) << 16) | bfr(ax);
}

// ---------------- Kernel P: fcW fp32 -> bf16 ----------------
__global__ __launch_bounds__(256) void k_prep(
    const float* __restrict__ w, unsigned short* __restrict__ wb, int n)
{
  const int i = blockIdx.x * 256 + threadIdx.x;
  if (i < n) wb[i] = (unsigned short)bfr(w[i]);
}

// ---------------- Kernel B (v5): MFMA GEMM, tanh epilogue, column-sum partials -------
// Wave owns a 16-node strip. B = whole 128x128 W in registers (8 jt x 4 kc frags).
// C/D mapping (verified): col j2 = lane&15, row = (lane>>4)*4 + q.
// Epilogue: 4-wave LDS block reduction -> one 128-float partial per block.
__global__ __launch_bounds__(256) void k_fc5(
    const unsigned short* __restrict__ eb1, const unsigned short* __restrict__ eb2,
    const unsigned short* __restrict__ wb, const float* __restrict__ fcb,
    float* __restrict__ part, int N)
{
  const int path = blockIdx.y;
  const unsigned short* __restrict__ eb = path ? eb2 : eb1;
  const int lane = threadIdx.x & 63;
  const int wid  = threadIdx.x >> 6;
  const int wave = blockIdx.x * 4 + wid;
  const int r  = lane & 15;
  const int hi = lane >> 4;

  bf16x8 B[8][4];
#pragma unroll
  for (int jt = 0; jt < 8; ++jt)
#pragma unroll
    for (int kc = 0; kc < 4; ++kc)
      B[jt][kc] = *(const bf16x8*)(wb + (size_t)(jt * 16 + r) * D + kc * 32 + hi * 8);

  float bias[8];
#pragma unroll
  for (int jt = 0; jt < 8; ++jt) bias[jt] = fcb[jt * 16 + r];

  float wsum[8];
#pragma unroll
  for (int jt = 0; jt < 8; ++jt) wsum[jt] = 0.f;

  const int nstrips = (N + 15) / 16;
  for (int st = wave; st < nstrips; st += NWAVES) {
    const int n0 = st * 16;
    int na = n0 + r;
    if (na >= N) na = N - 1;  // clamp keeps loads in-bounds; masked in epilogue
    const unsigned short* arow = eb + (size_t)na * D + hi * 8;
    bf16x8 A[4];
#pragma unroll
    for (int kc = 0; kc < 4; ++kc) A[kc] = *(const bf16x8*)(arow + kc * 32);

    f32x4 acc[8];
#pragma unroll
    for (int jt = 0; jt < 8; ++jt) acc[jt] = (f32x4){0.f, 0.f, 0.f, 0.f};
#pragma unroll
    for (int kc = 0; kc < 4; ++kc)
#pragma unroll
      for (int jt = 0; jt < 8; ++jt)
        acc[jt] = __builtin_amdgcn_mfma_f32_16x16x32_bf16(A[kc], B[jt][kc], acc[jt], 0, 0, 0);

#pragma unroll
    for (int jt = 0; jt < 8; ++jt) {
      float s = 0.f;
#pragma unroll
      for (int q = 0; q < 4; ++q) {
        const int node = n0 + hi * 4 + q;
        const float t = tanhf(acc[jt][q] + bias[jt]);
        s += (node < N) ? t : 0.f;
      }
      s += __shfl_xor(s, 16, 64);
      s += __shfl_xor(s, 32, 64);
      wsum[jt] += s;
    }
  }

  __shared__ float sd[4][D];
  if (lane < 16) {
#pragma unroll
    for (int jt = 0; jt < 8; ++jt) sd[wid][jt * 16 + lane] = wsum[jt];
  }
  __syncthreads();
  const int t = threadIdx.x;
  if (t < D) {
    const float v = sd[0][t] + sd[1][t] + sd[2][t] + sd[3][t];
    part[((size_t)path * NB2 + blockIdx.x) * D + t] = v;
  }
}

// ---------------- Kernel C: reduce partials -> sps -> beta (one block) ----------------
__global__ __launch_bounds__(256) void k_finish(
    const float* __restrict__ part, const float* __restrict__ att_inter,
    float* __restrict__ beta, float invN)
{
  const int t    = threadIdx.x;
  const int path = t >> 7;
  const int j    = t & 127;
  const int lane = t & 63;
  const int wid  = t >> 6;

  const float* __restrict__ p = part + (size_t)path * NB2 * D + j;
  float s = 0.f;
#pragma unroll 8
  for (int b = 0; b < NB2; ++b) s += p[(size_t)b * D];

  float v = (s * invN) * att_inter[j];
  v = wave_sum(v);

  __shared__ float red[4];
  if (lane == 0) red[wid] = v;
  __syncthreads();
  if (t == 0) {
    const float v0 = red[0] + red[1];
    const float v1 = red[2] + red[3];
    const float m = fmaxf(v0, v1);
    const float p0 = __expf(v0 - m), p1 = __expf(v1 - m);
    const float inv = 1.f / (p0 + p1);
    beta[0] = p0 * inv;
    beta[1] = p1 * inv;
  }
}

// ---------------- Kernel D: out = b0*e1 + b1*e2 (bf16 sources, fp32 out) -------------
__global__ __launch_bounds__(256) void k_combine(
    const uint2* __restrict__ eb1v, const uint2* __restrict__ eb2v,
    const float* __restrict__ beta, float* __restrict__ outp, int total4)
{
  const float b0 = beta[0], b1 = beta[1];
  float4* out = (float4*)outp;
  int i = blockIdx.x * 256 + threadIdx.x;
  const int stride = gridDim.x * 256;
  for (; i < total4; i += stride) {
    const uint2 a = eb1v[i], b = eb2v[i];
    float4 o;
    o.x = b0 * __uint_as_float(a.x << 16)         + b1 * __uint_as_float(b.x << 16);
    o.y = b0 * __uint_as_float(a.x & 0xFFFF0000u) + b1 * __uint_as_float(b.x & 0xFFFF0000u);
    o.z = b0 * __uint_as_float(a.y << 16)         + b1 * __uint_as_float(b.y << 16);
    o.w = b0 * __uint_as_float(a.y & 0xFFFF0000u) + b1 * __uint_as_float(b.y & 0xFFFF0000u);
    out[i] = o;
  }
}

extern "C" void kernel_launch(void* const* d_in, const int* in_sizes, int n_in,
                              void* d_out, int out_size, void* d_ws, size_t ws_size,
                              hipStream_t stream) {
  const float* h_ref     = (const float*)d_in[0];
  const float* h1        = (const float*)d_in[1];
  const float* h2        = (const float*)d_in[2];
  const int*   nei1      = (const int*)d_in[3];
  const int*   nei2      = (const int*)d_in[4];
  const float* att1      = (const float*)d_in[5];
  const float* att2      = (const float*)d_in[6];
  const float* fcW       = (const float*)d_in[7];
  const float* fcb       = (const float*)d_in[8];
  const float* att_inter = (const float*)d_in[9];

  const int N  = in_sizes[0] / D;
  const int M  = in_sizes[1] / D;
  const int S1 = in_sizes[3] / N;
  const int S2 = in_sizes[4] / N;

  unsigned short* eb1 = (unsigned short*)d_ws;                 // bf16 e1 [N][D]
  unsigned short* eb2 = eb1 + (size_t)N * D;                   // bf16 e2 [N][D]
  unsigned short* wb  = eb2 + (size_t)N * D;                   // bf16 W  [D][D]
  float* part = (float*)(wb + D * D);                          // [2][NB2][D]
  float* beta = part + (size_t)2 * NB2 * D;                    // 2 floats
  float* q1   = beta + 2;                                      // [N]
  float* q2   = q1 + N;                                        // [N]
  float* p1   = q2 + N;                                        // [M]
  float* p2   = p1 + M;                                        // [M]
  float* out  = (float*)d_out;

  k_prep<<<(D * D + 255) / 256, 256, 0, stream>>>(fcW, wb, D * D);

  const int rows = N + 2 * M;
  k_proj<<<(rows + 3) / 4, 256, 0, stream>>>(h_ref, h1, h2, att1, att2,
                                             q1, q2, p1, p2, N, M);

  const dim3 gA((N + 3) / 4);
  if (S1 == 20)      k_intra2<20><<<gA, 256, 0, stream>>>(q1, p1, h1, nei1, (unsigned*)eb1, N);
  else if (S1 == 10) k_intra2<10><<<gA, 256, 0, stream>>>(q1, p1, h1, nei1, (unsigned*)eb1, N);
  else               k_intra2_gen<<<gA, 256, 0, stream>>>(q1, p1, h1, nei1, (unsigned*)eb1, N, S1);

  if (S2 == 10)      k_intra2<10><<<gA, 256, 0, stream>>>(q2, p2, h2, nei2, (unsigned*)eb2, N);
  else if (S2 == 20) k_intra2<20><<<gA, 256, 0, stream>>>(q2, p2, h2, nei2, (unsigned*)eb2, N);
  else               k_intra2_gen<<<gA, 256, 0, stream>>>(q2, p2, h2, nei2, (unsigned*)eb2, N, S2);

  const dim3 gB(NB2, 2);
  k_fc5<<<gB, 256, 0, stream>>>(eb1, eb2, wb, fcb, part, N);

  k_finish<<<1, 256, 0, stream>>>(part, att_inter, beta, 1.0f / (float)N);

  const int total4 = N * D / 4;
  int gD = (total4 + 255) / 256;
  if (gD > 2048) gD = 2048;
  k_combine<<<gD, 256, 0, stream>>>((const uint2*)eb1, (const uint2*)eb2, beta, out, total4);
}

// Round 7
// 136.069 us; speedup vs baseline: 1.3310x; 1.3310x over previous
//
#include <hip/hip_runtime.h>
#include <hip/hip_bf16.h>
#include <math.h>

#define D 128
#define NB2 96            // blocks per path in k_fc5
#define NWAVES (NB2 * 4)  // waves per path

typedef __attribute__((ext_vector_type(8))) short bf16x8;
typedef __attribute__((ext_vector_type(4))) float f32x4;

__device__ __forceinline__ float wave_sum(float v) {
#pragma unroll
  for (int off = 32; off; off >>= 1) v += __shfl_xor(v, off, 64);
  return v;
}

// fp32 -> bf16 round-to-nearest-even (finite inputs)
__device__ __forceinline__ unsigned bfr(float f) {
  const unsigned u = __float_as_uint(f);
  return (u + 0x7FFFu + ((u >> 16) & 1u)) >> 16;
}

// ---------------- Kernel P0: projections q,p + bf16 copies of h1/h2 ----------------
// One wave per row. Rows [0,N): h_ref -> q1,q2. [N,N+M): h1 -> p1 + hb1. [N+M,N+2M): h2 -> p2 + hb2.
__global__ __launch_bounds__(256) void k_proj(
    const float* __restrict__ h_ref, const float* __restrict__ h1,
    const float* __restrict__ h2,
    const float* __restrict__ att1, const float* __restrict__ att2,
    float* __restrict__ q1, float* __restrict__ q2,
    float* __restrict__ p1, float* __restrict__ p2,
    unsigned* __restrict__ hb1u, unsigned* __restrict__ hb2u, int N, int M)
{
  const int lane = threadIdx.x & 63;
  const int r = blockIdx.x * 4 + (threadIdx.x >> 6);
  const int total = N + 2 * M;
  if (r >= total) return;
  if (r < N) {
    const float2 v  = *(const float2*)(h_ref + (size_t)r * D + 2 * lane);
    const float2 a1 = *(const float2*)(att1 + 2 * lane);
    const float2 a2 = *(const float2*)(att2 + 2 * lane);
    const float s1 = wave_sum(v.x * a1.x + v.y * a1.y);
    const float s2 = wave_sum(v.x * a2.x + v.y * a2.y);
    if (lane == 0) { q1[r] = s1; q2[r] = s2; }
  } else if (r < N + M) {
    const int m = r - N;
    const float2 v = *(const float2*)(h1 + (size_t)m * D + 2 * lane);
    const float2 a = *(const float2*)(att1 + D + 2 * lane);
    hb1u[(size_t)m * (D / 2) + lane] = (bfr(v.y) << 16) | bfr(v.x);
    const float s = wave_sum(v.x * a.x + v.y * a.y);
    if (lane == 0) p1[m] = s;
  } else {
    const int m = r - N - M;
    const float2 v = *(const float2*)(h2 + (size_t)m * D + 2 * lane);
    const float2 a = *(const float2*)(att2 + D + 2 * lane);
    hb2u[(size_t)m * (D / 2) + lane] = (bfr(v.y) << 16) | bfr(v.x);
    const float s = wave_sum(v.x * a.x + v.y * a.y);
    if (lane == 0) p2[m] = s;
  }
}

// ---------------- Kernel A (v3): intra attention, bf16 gathers ----------------
// One wave per node. Lane s<S gathers scalar p[nei_s]; softmax across lanes;
// neighbor-row gathers read 256B bf16 rows (4B/lane); weights via readlane.
template<int S>
__global__ __launch_bounds__(256) void k_intra3(
    const float* __restrict__ q, const float* __restrict__ p,
    const unsigned* __restrict__ hbu, const int* __restrict__ nei,
    unsigned* __restrict__ eb, int N)
{
  const int lane = threadIdx.x & 63;
  const int n = blockIdx.x * 4 + (threadIdx.x >> 6);
  if (n >= N) return;

  const int myidx = (lane < S) ? nei[(size_t)n * S + lane] : 0;
  const float pv = (lane < S) ? p[myidx] : 0.f;
  float x = q[n] + pv;
  x = x > 0.f ? x : 0.01f * x;          // leaky_relu
  if (lane >= S) x = -1e30f;
  float m = x;
#pragma unroll
  for (int off = 32; off; off >>= 1) m = fmaxf(m, __shfl_xor(m, off, 64));
  const float ex = (lane < S) ? __expf(x - m) : 0.f;
  float sum = ex;
#pragma unroll
  for (int off = 32; off; off >>= 1) sum += __shfl_xor(sum, off, 64);
  const float w = ex / sum;             // lane s holds w_s

  unsigned uu[S];
#pragma unroll
  for (int s = 0; s < S; ++s) {
    const int row = __shfl(myidx, s, 64);  // readlane: uniform row index
    uu[s] = hbu[(size_t)row * (D / 2) + lane];
  }
  float ax0 = 0.f, ay0 = 0.f, ax1 = 0.f, ay1 = 0.f;
#pragma unroll
  for (int s = 0; s < S; s += 2) {       // S even (10/20)
    const float w0 = __shfl(w, s, 64);
    const float w1 = __shfl(w, s + 1, 64);
    ax0 = fmaf(w0, __uint_as_float(uu[s] << 16), ax0);
    ay0 = fmaf(w0, __uint_as_float(uu[s] & 0xFFFF0000u), ay0);
    ax1 = fmaf(w1, __uint_as_float(uu[s + 1] << 16), ax1);
    ay1 = fmaf(w1, __uint_as_float(uu[s + 1] & 0xFFFF0000u), ay1);
  }
  float ex2 = ax0 + ax1, ey2 = ay0 + ay1;
  ex2 = ex2 > 0.f ? ex2 : expm1f(ex2);  // ELU
  ey2 = ey2 > 0.f ? ey2 : expm1f(ey2);
  eb[(size_t)n * (D / 2) + lane] = (bfr(ey2) << 16) | bfr(ex2);
}

// Generic fallback (runtime S, S <= 64)
__global__ __launch_bounds__(256) void k_intra3_gen(
    const float* __restrict__ q, const float* __restrict__ p,
    const unsigned* __restrict__ hbu, const int* __restrict__ nei,
    unsigned* __restrict__ eb, int N, int S)
{
  const int lane = threadIdx.x & 63;
  const int n = blockIdx.x * 4 + (threadIdx.x >> 6);
  if (n >= N) return;
  const int myidx = (lane < S) ? nei[(size_t)n * S + lane] : 0;
  const float pv = (lane < S) ? p[myidx] : 0.f;
  float x = q[n] + pv;
  x = x > 0.f ? x : 0.01f * x;
  if (lane >= S) x = -1e30f;
  float m = x;
#pragma unroll
  for (int off = 32; off; off >>= 1) m = fmaxf(m, __shfl_xor(m, off, 64));
  const float ex = (lane < S) ? __expf(x - m) : 0.f;
  float sum = ex;
#pragma unroll
  for (int off = 32; off; off >>= 1) sum += __shfl_xor(sum, off, 64);
  const float w = ex / sum;
  float ax = 0.f, ay = 0.f;
  for (int s = 0; s < S; ++s) {
    const int row = __shfl(myidx, s, 64);
    const float ws = __shfl(w, s, 64);
    const unsigned u = hbu[(size_t)row * (D / 2) + lane];
    ax = fmaf(ws, __uint_as_float(u << 16), ax);
    ay = fmaf(ws, __uint_as_float(u & 0xFFFF0000u), ay);
  }
  ax = ax > 0.f ? ax : expm1f(ax);
  ay = ay > 0.f ? ay : expm1f(ay);
  eb[(size_t)n * (D / 2) + lane] = (bfr(ay) << 16) | bfr(ax);
}

// ---------------- Kernel P: fcW fp32 -> bf16 ----------------
__global__ __launch_bounds__(256) void k_prep(
    const float* __restrict__ w, unsigned short* __restrict__ wb, int n)
{
  const int i = blockIdx.x * 256 + threadIdx.x;
  if (i < n) wb[i] = (unsigned short)bfr(w[i]);
}

// ---------------- Kernel B (v5): MFMA GEMM, tanh epilogue, column-sum partials -------
__global__ __launch_bounds__(256) void k_fc5(
    const unsigned short* __restrict__ eb1, const unsigned short* __restrict__ eb2,
    const unsigned short* __restrict__ wb, const float* __restrict__ fcb,
    float* __restrict__ part, int N)
{
  const int path = blockIdx.y;
  const unsigned short* __restrict__ eb = path ? eb2 : eb1;
  const int lane = threadIdx.x & 63;
  const int wid  = threadIdx.x >> 6;
  const int wave = blockIdx.x * 4 + wid;
  const int r  = lane & 15;
  const int hi = lane >> 4;

  bf16x8 B[8][4];
#pragma unroll
  for (int jt = 0; jt < 8; ++jt)
#pragma unroll
    for (int kc = 0; kc < 4; ++kc)
      B[jt][kc] = *(const bf16x8*)(wb + (size_t)(jt * 16 + r) * D + kc * 32 + hi * 8);

  float bias[8];
#pragma unroll
  for (int jt = 0; jt < 8; ++jt) bias[jt] = fcb[jt * 16 + r];

  float wsum[8];
#pragma unroll
  for (int jt = 0; jt < 8; ++jt) wsum[jt] = 0.f;

  const int nstrips = (N + 15) / 16;
  for (int st = wave; st < nstrips; st += NWAVES) {
    const int n0 = st * 16;
    int na = n0 + r;
    if (na >= N) na = N - 1;  // clamp keeps loads in-bounds; masked in epilogue
    const unsigned short* arow = eb + (size_t)na * D + hi * 8;
    bf16x8 A[4];
#pragma unroll
    for (int kc = 0; kc < 4; ++kc) A[kc] = *(const bf16x8*)(arow + kc * 32);

    f32x4 acc[8];
#pragma unroll
    for (int jt = 0; jt < 8; ++jt) acc[jt] = (f32x4){0.f, 0.f, 0.f, 0.f};
#pragma unroll
    for (int kc = 0; kc < 4; ++kc)
#pragma unroll
      for (int jt = 0; jt < 8; ++jt)
        acc[jt] = __builtin_amdgcn_mfma_f32_16x16x32_bf16(A[kc], B[jt][kc], acc[jt], 0, 0, 0);

#pragma unroll
    for (int jt = 0; jt < 8; ++jt) {
      float s = 0.f;
#pragma unroll
      for (int q = 0; q < 4; ++q) {
        const int node = n0 + hi * 4 + q;
        const float t = tanhf(acc[jt][q] + bias[jt]);
        s += (node < N) ? t : 0.f;
      }
      s += __shfl_xor(s, 16, 64);
      s += __shfl_xor(s, 32, 64);
      wsum[jt] += s;
    }
  }

  __shared__ float sd[4][D];
  if (lane < 16) {
#pragma unroll
    for (int jt = 0; jt < 8; ++jt) sd[wid][jt * 16 + lane] = wsum[jt];
  }
  __syncthreads();
  const int t = threadIdx.x;
  if (t < D) {
    const float v = sd[0][t] + sd[1][t] + sd[2][t] + sd[3][t];
    part[((size_t)path * NB2 + blockIdx.x) * D + t] = v;
  }
}

// ---------------- Kernel C: reduce partials -> sps -> beta (one block) ----------------
__global__ __launch_bounds__(256) void k_finish(
    const float* __restrict__ part, const float* __restrict__ att_inter,
    float* __restrict__ beta, float invN)
{
  const int t    = threadIdx.x;
  const int path = t >> 7;
  const int j    = t & 127;
  const int lane = t & 63;
  const int wid  = t >> 6;

  const float* __restrict__ p = part + (size_t)path * NB2 * D + j;
  float s = 0.f;
#pragma unroll 8
  for (int b = 0; b < NB2; ++b) s += p[(size_t)b * D];

  float v = (s * invN) * att_inter[j];
  v = wave_sum(v);

  __shared__ float red[4];
  if (lane == 0) red[wid] = v;
  __syncthreads();
  if (t == 0) {
    const float v0 = red[0] + red[1];
    const float v1 = red[2] + red[3];
    const float m = fmaxf(v0, v1);
    const float p0 = __expf(v0 - m), p1 = __expf(v1 - m);
    const float inv = 1.f / (p0 + p1);
    beta[0] = p0 * inv;
    beta[1] = p1 * inv;
  }
}

// ---------------- Kernel D: out = b0*e1 + b1*e2 (bf16 sources, fp32 out) -------------
__global__ __launch_bounds__(256) void k_combine(
    const uint2* __restrict__ eb1v, const uint2* __restrict__ eb2v,
    const float* __restrict__ beta, float* __restrict__ outp, int total4)
{
  const float b0 = beta[0], b1 = beta[1];
  float4* out = (float4*)outp;
  int i = blockIdx.x * 256 + threadIdx.x;
  const int stride = gridDim.x * 256;
  for (; i < total4; i += stride) {
    const uint2 a = eb1v[i], b = eb2v[i];
    float4 o;
    o.x = b0 * __uint_as_float(a.x << 16)         + b1 * __uint_as_float(b.x << 16);
    o.y = b0 * __uint_as_float(a.x & 0xFFFF0000u) + b1 * __uint_as_float(b.x & 0xFFFF0000u);
    o.z = b0 * __uint_as_float(a.y << 16)         + b1 * __uint_as_float(b.y << 16);
    o.w = b0 * __uint_as_float(a.y & 0xFFFF0000u) + b1 * __uint_as_float(b.y & 0xFFFF0000u);
    out[i] = o;
  }
}

extern "C" void kernel_launch(void* const* d_in, const int* in_sizes, int n_in,
                              void* d_out, int out_size, void* d_ws, size_t ws_size,
                              hipStream_t stream) {
  const float* h_ref     = (const float*)d_in[0];
  const float* h1        = (const float*)d_in[1];
  const float* h2        = (const float*)d_in[2];
  const int*   nei1      = (const int*)d_in[3];
  const int*   nei2      = (const int*)d_in[4];
  const float* att1      = (const float*)d_in[5];
  const float* att2      = (const float*)d_in[6];
  const float* fcW       = (const float*)d_in[7];
  const float* fcb       = (const float*)d_in[8];
  const float* att_inter = (const float*)d_in[9];

  const int N  = in_sizes[0] / D;
  const int M  = in_sizes[1] / D;
  const int S1 = in_sizes[3] / N;
  const int S2 = in_sizes[4] / N;
  const size_t MX = (size_t)(M > N ? M : N) * D;

  // bufX serves as hb1 (bf16 h1) during path-1, then is overwritten as eb2 by
  // path-2's intra (hb1 is dead by then). Saves 12.8 MB of workspace.
  unsigned short* bufX = (unsigned short*)d_ws;                // hb1 -> eb2 [MX]
  unsigned short* hb2  = bufX + MX;                            // bf16 h2 [M*D]
  unsigned short* eb1  = hb2 + (size_t)M * D;                  // bf16 e1 [N*D]
  unsigned short* wb   = eb1 + (size_t)N * D;                  // bf16 W  [D*D]
  float* part = (float*)(wb + D * D);                          // [2][NB2][D]
  float* beta = part + (size_t)2 * NB2 * D;                    // 2 floats
  float* q1   = beta + 2;                                      // [N]
  float* q2   = q1 + N;                                        // [N]
  float* p1   = q2 + N;                                        // [M]
  float* p2   = p1 + M;                                        // [M]
  float* out  = (float*)d_out;

  unsigned* hb1u = (unsigned*)bufX;
  unsigned* hb2u = (unsigned*)hb2;
  unsigned* eb1u = (unsigned*)eb1;
  unsigned* eb2u = (unsigned*)bufX;

  k_prep<<<(D * D + 255) / 256, 256, 0, stream>>>(fcW, wb, D * D);

  const int rows = N + 2 * M;
  k_proj<<<(rows + 3) / 4, 256, 0, stream>>>(h_ref, h1, h2, att1, att2,
                                             q1, q2, p1, p2, hb1u, hb2u, N, M);

  const dim3 gA((N + 3) / 4);
  if (S1 == 20)      k_intra3<20><<<gA, 256, 0, stream>>>(q1, p1, hb1u, nei1, eb1u, N);
  else if (S1 == 10) k_intra3<10><<<gA, 256, 0, stream>>>(q1, p1, hb1u, nei1, eb1u, N);
  else               k_intra3_gen<<<gA, 256, 0, stream>>>(q1, p1, hb1u, nei1, eb1u, N, S1);

  if (S2 == 10)      k_intra3<10><<<gA, 256, 0, stream>>>(q2, p2, hb2u, nei2, eb2u, N);
  else if (S2 == 20) k_intra3<20><<<gA, 256, 0, stream>>>(q2, p2, hb2u, nei2, eb2u, N);
  else               k_intra3_gen<<<gA, 256, 0, stream>>>(q2, p2, hb2u, nei2, eb2u, N, S2);

  const dim3 gB(NB2, 2);
  k_fc5<<<gB, 256, 0, stream>>>(eb1, (unsigned short*)bufX, wb, fcb, part, N);

  k_finish<<<1, 256, 0, stream>>>(part, att_inter, beta, 1.0f / (float)N);

  const int total4 = N * D / 4;
  int gD = (total4 + 255) / 256;
  if (gD > 2048) gD = 2048;
  k_combine<<<gD, 256, 0, stream>>>((const uint2*)eb1, (const uint2*)bufX, beta, out, total4);
}

// Round 8
// 134.493 us; speedup vs baseline: 1.3466x; 1.0117x over previous
//
#include <hip/hip_runtime.h>
#include <hip/hip_bf16.h>
#include <math.h>

#define D 128
#define NB2 392           // blocks per path in k_fc5 (784 total = ~3/CU)
#define NWAVES (NB2 * 4)  // waves per path

typedef __attribute__((ext_vector_type(8))) short bf16x8;
typedef __attribute__((ext_vector_type(4))) float f32x4;

__device__ __forceinline__ float wave_sum(float v) {
#pragma unroll
  for (int off = 32; off; off >>= 1) v += __shfl_xor(v, off, 64);
  return v;
}

// fp32 -> bf16 round-to-nearest-even (finite inputs)
__device__ __forceinline__ unsigned bfr(float f) {
  const unsigned u = __float_as_uint(f);
  return (u + 0x7FFFu + ((u >> 16) & 1u)) >> 16;
}

// tanh(x) = 1 - 2/(e^{2x}+1); correct limits at +/-inf, ~1e-7 abs error.
__device__ __forceinline__ float fast_tanh(float x) {
  const float ez = __expf(2.f * x);
  return 1.f - 2.f / (ez + 1.f);
}

// ---------------- Kernel P0: projections q,p + bf16 copies of h1/h2 ----------------
__global__ __launch_bounds__(256) void k_proj(
    const float* __restrict__ h_ref, const float* __restrict__ h1,
    const float* __restrict__ h2,
    const float* __restrict__ att1, const float* __restrict__ att2,
    float* __restrict__ q1, float* __restrict__ q2,
    float* __restrict__ p1, float* __restrict__ p2,
    unsigned* __restrict__ hb1u, unsigned* __restrict__ hb2u, int N, int M)
{
  const int lane = threadIdx.x & 63;
  const int r = blockIdx.x * 4 + (threadIdx.x >> 6);
  const int total = N + 2 * M;
  if (r >= total) return;
  if (r < N) {
    const float2 v  = *(const float2*)(h_ref + (size_t)r * D + 2 * lane);
    const float2 a1 = *(const float2*)(att1 + 2 * lane);
    const float2 a2 = *(const float2*)(att2 + 2 * lane);
    const float s1 = wave_sum(v.x * a1.x + v.y * a1.y);
    const float s2 = wave_sum(v.x * a2.x + v.y * a2.y);
    if (lane == 0) { q1[r] = s1; q2[r] = s2; }
  } else if (r < N + M) {
    const int m = r - N;
    const float2 v = *(const float2*)(h1 + (size_t)m * D + 2 * lane);
    const float2 a = *(const float2*)(att1 + D + 2 * lane);
    hb1u[(size_t)m * (D / 2) + lane] = (bfr(v.y) << 16) | bfr(v.x);
    const float s = wave_sum(v.x * a.x + v.y * a.y);
    if (lane == 0) p1[m] = s;
  } else {
    const int m = r - N - M;
    const float2 v = *(const float2*)(h2 + (size_t)m * D + 2 * lane);
    const float2 a = *(const float2*)(att2 + D + 2 * lane);
    hb2u[(size_t)m * (D / 2) + lane] = (bfr(v.y) << 16) | bfr(v.x);
    const float s = wave_sum(v.x * a.x + v.y * a.y);
    if (lane == 0) p2[m] = s;
  }
}

// ---------------- Kernel A (v3): intra attention, bf16 gathers ----------------
template<int S>
__global__ __launch_bounds__(256) void k_intra3(
    const float* __restrict__ q, const float* __restrict__ p,
    const unsigned* __restrict__ hbu, const int* __restrict__ nei,
    unsigned* __restrict__ eb, int N)
{
  const int lane = threadIdx.x & 63;
  const int n = blockIdx.x * 4 + (threadIdx.x >> 6);
  if (n >= N) return;

  const int myidx = (lane < S) ? nei[(size_t)n * S + lane] : 0;
  const float pv = (lane < S) ? p[myidx] : 0.f;
  float x = q[n] + pv;
  x = x > 0.f ? x : 0.01f * x;          // leaky_relu
  if (lane >= S) x = -1e30f;
  float m = x;
#pragma unroll
  for (int off = 32; off; off >>= 1) m = fmaxf(m, __shfl_xor(m, off, 64));
  const float ex = (lane < S) ? __expf(x - m) : 0.f;
  float sum = ex;
#pragma unroll
  for (int off = 32; off; off >>= 1) sum += __shfl_xor(sum, off, 64);
  const float w = ex / sum;             // lane s holds w_s

  unsigned uu[S];
#pragma unroll
  for (int s = 0; s < S; ++s) {
    const int row = __shfl(myidx, s, 64);  // readlane: uniform row index
    uu[s] = hbu[(size_t)row * (D / 2) + lane];
  }
  float ax0 = 0.f, ay0 = 0.f, ax1 = 0.f, ay1 = 0.f;
#pragma unroll
  for (int s = 0; s < S; s += 2) {       // S even (10/20)
    const float w0 = __shfl(w, s, 64);
    const float w1 = __shfl(w, s + 1, 64);
    ax0 = fmaf(w0, __uint_as_float(uu[s] << 16), ax0);
    ay0 = fmaf(w0, __uint_as_float(uu[s] & 0xFFFF0000u), ay0);
    ax1 = fmaf(w1, __uint_as_float(uu[s + 1] << 16), ax1);
    ay1 = fmaf(w1, __uint_as_float(uu[s + 1] & 0xFFFF0000u), ay1);
  }
  float ex2 = ax0 + ax1, ey2 = ay0 + ay1;
  ex2 = ex2 > 0.f ? ex2 : expm1f(ex2);  // ELU
  ey2 = ey2 > 0.f ? ey2 : expm1f(ey2);
  eb[(size_t)n * (D / 2) + lane] = (bfr(ey2) << 16) | bfr(ex2);
}

// Generic fallback (runtime S, S <= 64)
__global__ __launch_bounds__(256) void k_intra3_gen(
    const float* __restrict__ q, const float* __restrict__ p,
    const unsigned* __restrict__ hbu, const int* __restrict__ nei,
    unsigned* __restrict__ eb, int N, int S)
{
  const int lane = threadIdx.x & 63;
  const int n = blockIdx.x * 4 + (threadIdx.x >> 6);
  if (n >= N) return;
  const int myidx = (lane < S) ? nei[(size_t)n * S + lane] : 0;
  const float pv = (lane < S) ? p[myidx] : 0.f;
  float x = q[n] + pv;
  x = x > 0.f ? x : 0.01f * x;
  if (lane >= S) x = -1e30f;
  float m = x;
#pragma unroll
  for (int off = 32; off; off >>= 1) m = fmaxf(m, __shfl_xor(m, off, 64));
  const float ex = (lane < S) ? __expf(x - m) : 0.f;
  float sum = ex;
#pragma unroll
  for (int off = 32; off; off >>= 1) sum += __shfl_xor(sum, off, 64);
  const float w = ex / sum;
  float ax = 0.f, ay = 0.f;
  for (int s = 0; s < S; ++s) {
    const int row = __shfl(myidx, s, 64);
    const float ws = __shfl(w, s, 64);
    const unsigned u = hbu[(size_t)row * (D / 2) + lane];
    ax = fmaf(ws, __uint_as_float(u << 16), ax);
    ay = fmaf(ws, __uint_as_float(u & 0xFFFF0000u), ay);
  }
  ax = ax > 0.f ? ax : expm1f(ax);
  ay = ay > 0.f ? ay : expm1f(ay);
  eb[(size_t)n * (D / 2) + lane] = (bfr(ay) << 16) | bfr(ax);
}

// ---------------- Kernel P: fcW fp32 -> bf16 ----------------
__global__ __launch_bounds__(256) void k_prep(
    const float* __restrict__ w, unsigned short* __restrict__ wb, int n)
{
  const int i = blockIdx.x * 256 + threadIdx.x;
  if (i < n) wb[i] = (unsigned short)bfr(w[i]);
}

// ---------------- Kernel B (v6): MFMA GEMM, fast-tanh epilogue, partials -------------
__global__ __launch_bounds__(256) void k_fc5(
    const unsigned short* __restrict__ eb1, const unsigned short* __restrict__ eb2,
    const unsigned short* __restrict__ wb, const float* __restrict__ fcb,
    float* __restrict__ part, int N)
{
  const int path = blockIdx.y;
  const unsigned short* __restrict__ eb = path ? eb2 : eb1;
  const int lane = threadIdx.x & 63;
  const int wid  = threadIdx.x >> 6;
  const int wave = blockIdx.x * 4 + wid;
  const int r  = lane & 15;
  const int hi = lane >> 4;

  bf16x8 B[8][4];
#pragma unroll
  for (int jt = 0; jt < 8; ++jt)
#pragma unroll
    for (int kc = 0; kc < 4; ++kc)
      B[jt][kc] = *(const bf16x8*)(wb + (size_t)(jt * 16 + r) * D + kc * 32 + hi * 8);

  float bias[8];
#pragma unroll
  for (int jt = 0; jt < 8; ++jt) bias[jt] = fcb[jt * 16 + r];

  float wsum[8];
#pragma unroll
  for (int jt = 0; jt < 8; ++jt) wsum[jt] = 0.f;

  const int nstrips = (N + 15) / 16;
  for (int st = wave; st < nstrips; st += NWAVES) {
    const int n0 = st * 16;
    int na = n0 + r;
    if (na >= N) na = N - 1;  // clamp keeps loads in-bounds; masked in epilogue
    const unsigned short* arow = eb + (size_t)na * D + hi * 8;
    bf16x8 A[4];
#pragma unroll
    for (int kc = 0; kc < 4; ++kc) A[kc] = *(const bf16x8*)(arow + kc * 32);

    f32x4 acc[8];
#pragma unroll
    for (int jt = 0; jt < 8; ++jt) acc[jt] = (f32x4){0.f, 0.f, 0.f, 0.f};
#pragma unroll
    for (int kc = 0; kc < 4; ++kc)
#pragma unroll
      for (int jt = 0; jt < 8; ++jt)
        acc[jt] = __builtin_amdgcn_mfma_f32_16x16x32_bf16(A[kc], B[jt][kc], acc[jt], 0, 0, 0);

#pragma unroll
    for (int jt = 0; jt < 8; ++jt) {
      float s = 0.f;
#pragma unroll
      for (int q = 0; q < 4; ++q) {
        const int node = n0 + hi * 4 + q;
        const float t = fast_tanh(acc[jt][q] + bias[jt]);
        s += (node < N) ? t : 0.f;
      }
      s += __shfl_xor(s, 16, 64);
      s += __shfl_xor(s, 32, 64);
      wsum[jt] += s;
    }
  }

  __shared__ float sd[4][D];
  if (lane < 16) {
#pragma unroll
    for (int jt = 0; jt < 8; ++jt) sd[wid][jt * 16 + lane] = wsum[jt];
  }
  __syncthreads();
  const int t = threadIdx.x;
  if (t < D) {
    const float v = sd[0][t] + sd[1][t] + sd[2][t] + sd[3][t];
    part[((size_t)path * NB2 + blockIdx.x) * D + t] = v;
  }
}

// ---------------- Kernel C: reduce partials -> sps -> beta (one block) ----------------
__global__ __launch_bounds__(256) void k_finish(
    const float* __restrict__ part, const float* __restrict__ att_inter,
    float* __restrict__ beta, float invN)
{
  const int t    = threadIdx.x;
  const int path = t >> 7;
  const int j    = t & 127;
  const int lane = t & 63;
  const int wid  = t >> 6;

  const float* __restrict__ p = part + (size_t)path * NB2 * D + j;
  float s = 0.f;
#pragma unroll 8
  for (int b = 0; b < NB2; ++b) s += p[(size_t)b * D];

  float v = (s * invN) * att_inter[j];
  v = wave_sum(v);

  __shared__ float red[4];
  if (lane == 0) red[wid] = v;
  __syncthreads();
  if (t == 0) {
    const float v0 = red[0] + red[1];
    const float v1 = red[2] + red[3];
    const float m = fmaxf(v0, v1);
    const float p0 = __expf(v0 - m), p1 = __expf(v1 - m);
    const float inv = 1.f / (p0 + p1);
    beta[0] = p0 * inv;
    beta[1] = p1 * inv;
  }
}

// ---------------- Kernel D: out = b0*e1 + b1*e2 (bf16 sources, fp32 out) -------------
__global__ __launch_bounds__(256) void k_combine(
    const uint2* __restrict__ eb1v, const uint2* __restrict__ eb2v,
    const float* __restrict__ beta, float* __restrict__ outp, int total4)
{
  const float b0 = beta[0], b1 = beta[1];
  float4* out = (float4*)outp;
  int i = blockIdx.x * 256 + threadIdx.x;
  const int stride = gridDim.x * 256;
  for (; i < total4; i += stride) {
    const uint2 a = eb1v[i], b = eb2v[i];
    float4 o;
    o.x = b0 * __uint_as_float(a.x << 16)         + b1 * __uint_as_float(b.x << 16);
    o.y = b0 * __uint_as_float(a.x & 0xFFFF0000u) + b1 * __uint_as_float(b.x & 0xFFFF0000u);
    o.z = b0 * __uint_as_float(a.y << 16)         + b1 * __uint_as_float(b.y << 16);
    o.w = b0 * __uint_as_float(a.y & 0xFFFF0000u) + b1 * __uint_as_float(b.y & 0xFFFF0000u);
    out[i] = o;
  }
}

extern "C" void kernel_launch(void* const* d_in, const int* in_sizes, int n_in,
                              void* d_out, int out_size, void* d_ws, size_t ws_size,
                              hipStream_t stream) {
  const float* h_ref     = (const float*)d_in[0];
  const float* h1        = (const float*)d_in[1];
  const float* h2        = (const float*)d_in[2];
  const int*   nei1      = (const int*)d_in[3];
  const int*   nei2      = (const int*)d_in[4];
  const float* att1      = (const float*)d_in[5];
  const float* att2      = (const float*)d_in[6];
  const float* fcW       = (const float*)d_in[7];
  const float* fcb       = (const float*)d_in[8];
  const float* att_inter = (const float*)d_in[9];

  const int N  = in_sizes[0] / D;
  const int M  = in_sizes[1] / D;
  const int S1 = in_sizes[3] / N;
  const int S2 = in_sizes[4] / N;
  const size_t MX = (size_t)(M > N ? M : N) * D;

  // bufX serves as hb1 (bf16 h1) during path-1, then is overwritten as eb2 by
  // path-2's intra (hb1 is dead by then).
  unsigned short* bufX = (unsigned short*)d_ws;                // hb1 -> eb2 [MX]
  unsigned short* hb2  = bufX + MX;                            // bf16 h2 [M*D]
  unsigned short* eb1  = hb2 + (size_t)M * D;                  // bf16 e1 [N*D]
  unsigned short* wb   = eb1 + (size_t)N * D;                  // bf16 W  [D*D]
  float* part = (float*)(wb + D * D);                          // [2][NB2][D]
  float* beta = part + (size_t)2 * NB2 * D;                    // 2 floats
  float* q1   = beta + 2;                                      // [N]
  float* q2   = q1 + N;                                        // [N]
  float* p1   = q2 + N;                                        // [M]
  float* p2   = p1 + M;                                        // [M]
  float* out  = (float*)d_out;

  unsigned* hb1u = (unsigned*)bufX;
  unsigned* hb2u = (unsigned*)hb2;
  unsigned* eb1u = (unsigned*)eb1;
  unsigned* eb2u = (unsigned*)bufX;

  k_prep<<<(D * D + 255) / 256, 256, 0, stream>>>(fcW, wb, D * D);

  const int rows = N + 2 * M;
  k_proj<<<(rows + 3) / 4, 256, 0, stream>>>(h_ref, h1, h2, att1, att2,
                                             q1, q2, p1, p2, hb1u, hb2u, N, M);

  const dim3 gA((N + 3) / 4);
  if (S1 == 20)      k_intra3<20><<<gA, 256, 0, stream>>>(q1, p1, hb1u, nei1, eb1u, N);
  else if (S1 == 10) k_intra3<10><<<gA, 256, 0, stream>>>(q1, p1, hb1u, nei1, eb1u, N);
  else               k_intra3_gen<<<gA, 256, 0, stream>>>(q1, p1, hb1u, nei1, eb1u, N, S1);

  if (S2 == 10)      k_intra3<10><<<gA, 256, 0, stream>>>(q2, p2, hb2u, nei2, eb2u, N);
  else if (S2 == 20) k_intra3<20><<<gA, 256, 0, stream>>>(q2, p2, hb2u, nei2, eb2u, N);
  else               k_intra3_gen<<<gA, 256, 0, stream>>>(q2, p2, hb2u, nei2, eb2u, N, S2);

  const dim3 gB(NB2, 2);
  k_fc5<<<gB, 256, 0, stream>>>(eb1, (unsigned short*)bufX, wb, fcb, part, N);

  k_finish<<<1, 256, 0, stream>>>(part, att_inter, beta, 1.0f / (float)N);

  const int total4 = N * D / 4;
  int gD = (total4 + 255) / 256;
  if (gD > 2048) gD = 2048;
  k_combine<<<gD, 256, 0, stream>>>((const uint2*)eb1, (const uint2*)bufX, beta, out, total4);
}

// Round 9
// 119.338 us; speedup vs baseline: 1.5176x; 1.1270x over previous
//
#include <hip/hip_runtime.h>
#include <hip/hip_bf16.h>
#include <math.h>

#define D 128
#define NB2 392           // blocks per path in k_fc5 (784 total = ~3/CU)
#define NWAVES (NB2 * 4)  // waves per path

typedef __attribute__((ext_vector_type(8))) short bf16x8;
typedef __attribute__((ext_vector_type(4))) float f32x4;

__device__ __forceinline__ float wave_sum(float v) {
#pragma unroll
  for (int off = 32; off; off >>= 1) v += __shfl_xor(v, off, 64);
  return v;
}

// fp32 -> bf16 round-to-nearest-even (finite inputs)
__device__ __forceinline__ unsigned bfr(float f) {
  const unsigned u = __float_as_uint(f);
  return (u + 0x7FFFu + ((u >> 16) & 1u)) >> 16;
}

// tanh(x) = 1 - 2/(e^{2x}+1); correct limits at +/-inf, ~1e-7 abs error.
__device__ __forceinline__ float fast_tanh(float x) {
  const float ez = __expf(2.f * x);
  return 1.f - 2.f / (ez + 1.f);
}

// ---------------- Kernel P0: projections q,p + bf16 copies of h1/h2 + fcW->bf16 ------
// Rows [0,N): h_ref -> q1,q2. [N,N+M): h1 -> p1 + hb1. [N+M,N+2M): h2 -> p2 + hb2.
// Rows [N+2M, N+2M+64): convert fcW (256 elems per wave-row).
__global__ __launch_bounds__(256) void k_proj(
    const float* __restrict__ h_ref, const float* __restrict__ h1,
    const float* __restrict__ h2,
    const float* __restrict__ att1, const float* __restrict__ att2,
    const float* __restrict__ fcW, unsigned short* __restrict__ wb,
    float* __restrict__ q1, float* __restrict__ q2,
    float* __restrict__ p1, float* __restrict__ p2,
    unsigned* __restrict__ hb1u, unsigned* __restrict__ hb2u, int N, int M)
{
  const int lane = threadIdx.x & 63;
  const int r = blockIdx.x * 4 + (threadIdx.x >> 6);
  const int total = N + 2 * M + 64;
  if (r >= total) return;
  if (r < N) {
    const float2 v  = *(const float2*)(h_ref + (size_t)r * D + 2 * lane);
    const float2 a1 = *(const float2*)(att1 + 2 * lane);
    const float2 a2 = *(const float2*)(att2 + 2 * lane);
    const float s1 = wave_sum(v.x * a1.x + v.y * a1.y);
    const float s2 = wave_sum(v.x * a2.x + v.y * a2.y);
    if (lane == 0) { q1[r] = s1; q2[r] = s2; }
  } else if (r < N + M) {
    const int m = r - N;
    const float2 v = *(const float2*)(h1 + (size_t)m * D + 2 * lane);
    const float2 a = *(const float2*)(att1 + D + 2 * lane);
    hb1u[(size_t)m * (D / 2) + lane] = (bfr(v.y) << 16) | bfr(v.x);
    const float s = wave_sum(v.x * a.x + v.y * a.y);
    if (lane == 0) p1[m] = s;
  } else if (r < N + 2 * M) {
    const int m = r - N - M;
    const float2 v = *(const float2*)(h2 + (size_t)m * D + 2 * lane);
    const float2 a = *(const float2*)(att2 + D + 2 * lane);
    hb2u[(size_t)m * (D / 2) + lane] = (bfr(v.y) << 16) | bfr(v.x);
    const float s = wave_sum(v.x * a.x + v.y * a.y);
    if (lane == 0) p2[m] = s;
  } else {
    const int base = (r - (N + 2 * M)) * 256 + lane * 4;  // D*D = 16384 = 64*256
    const float4 v = *(const float4*)(fcW + base);
    ushort4 o;
    o.x = (unsigned short)bfr(v.x); o.y = (unsigned short)bfr(v.y);
    o.z = (unsigned short)bfr(v.z); o.w = (unsigned short)bfr(v.w);
    *(ushort4*)(wb + base) = o;
  }
}

// ---------------- intra attention body (bf16 gathers) ----------------
template<int S>
__device__ __forceinline__ void intra_body(
    const float* __restrict__ q, const float* __restrict__ p,
    const unsigned* __restrict__ hbu, const int* __restrict__ nei,
    unsigned* __restrict__ eb, int N, int n, int lane)
{
  const int myidx = (lane < S) ? nei[(size_t)n * S + lane] : 0;
  const float pv = (lane < S) ? p[myidx] : 0.f;
  float x = q[n] + pv;
  x = x > 0.f ? x : 0.01f * x;          // leaky_relu
  if (lane >= S) x = -1e30f;
  float m = x;
#pragma unroll
  for (int off = 32; off; off >>= 1) m = fmaxf(m, __shfl_xor(m, off, 64));
  const float ex = (lane < S) ? __expf(x - m) : 0.f;
  float sum = ex;
#pragma unroll
  for (int off = 32; off; off >>= 1) sum += __shfl_xor(sum, off, 64);
  const float w = ex / sum;             // lane s holds w_s

  unsigned uu[S];
#pragma unroll
  for (int s = 0; s < S; ++s) {
    const int row = __shfl(myidx, s, 64);  // readlane: uniform row index
    uu[s] = hbu[(size_t)row * (D / 2) + lane];
  }
  float ax0 = 0.f, ay0 = 0.f, ax1 = 0.f, ay1 = 0.f;
#pragma unroll
  for (int s = 0; s < S; s += 2) {       // S even (10/20)
    const float w0 = __shfl(w, s, 64);
    const float w1 = __shfl(w, s + 1, 64);
    ax0 = fmaf(w0, __uint_as_float(uu[s] << 16), ax0);
    ay0 = fmaf(w0, __uint_as_float(uu[s] & 0xFFFF0000u), ay0);
    ax1 = fmaf(w1, __uint_as_float(uu[s + 1] << 16), ax1);
    ay1 = fmaf(w1, __uint_as_float(uu[s + 1] & 0xFFFF0000u), ay1);
  }
  float ex2 = ax0 + ax1, ey2 = ay0 + ay1;
  ex2 = ex2 > 0.f ? ex2 : expm1f(ex2);  // ELU
  ey2 = ey2 > 0.f ? ey2 : expm1f(ey2);
  eb[(size_t)n * (D / 2) + lane] = (bfr(ey2) << 16) | bfr(ex2);
}

// Both paths in one launch: blockIdx.y = path. Tails overlap; one launch gap saved.
template<int SA, int SB>
__global__ __launch_bounds__(256) void k_intra_dual(
    const float* __restrict__ q1, const float* __restrict__ p1,
    const unsigned* __restrict__ hb1, const int* __restrict__ nei1,
    unsigned* __restrict__ eb1,
    const float* __restrict__ q2, const float* __restrict__ p2,
    const unsigned* __restrict__ hb2, const int* __restrict__ nei2,
    unsigned* __restrict__ eb2, int N)
{
  const int lane = threadIdx.x & 63;
  const int n = blockIdx.x * 4 + (threadIdx.x >> 6);
  if (n >= N) return;
  if (blockIdx.y == 0) intra_body<SA>(q1, p1, hb1, nei1, eb1, N, n, lane);
  else                 intra_body<SB>(q2, p2, hb2, nei2, eb2, N, n, lane);
}

// Generic fallback (runtime S, S <= 64)
__global__ __launch_bounds__(256) void k_intra3_gen(
    const float* __restrict__ q, const float* __restrict__ p,
    const unsigned* __restrict__ hbu, const int* __restrict__ nei,
    unsigned* __restrict__ eb, int N, int S)
{
  const int lane = threadIdx.x & 63;
  const int n = blockIdx.x * 4 + (threadIdx.x >> 6);
  if (n >= N) return;
  const int myidx = (lane < S) ? nei[(size_t)n * S + lane] : 0;
  const float pv = (lane < S) ? p[myidx] : 0.f;
  float x = q[n] + pv;
  x = x > 0.f ? x : 0.01f * x;
  if (lane >= S) x = -1e30f;
  float m = x;
#pragma unroll
  for (int off = 32; off; off >>= 1) m = fmaxf(m, __shfl_xor(m, off, 64));
  const float ex = (lane < S) ? __expf(x - m) : 0.f;
  float sum = ex;
#pragma unroll
  for (int off = 32; off; off >>= 1) sum += __shfl_xor(sum, off, 64);
  const float w = ex / sum;
  float ax = 0.f, ay = 0.f;
  for (int s = 0; s < S; ++s) {
    const int row = __shfl(myidx, s, 64);
    const float ws = __shfl(w, s, 64);
    const unsigned u = hbu[(size_t)row * (D / 2) + lane];
    ax = fmaf(ws, __uint_as_float(u << 16), ax);
    ay = fmaf(ws, __uint_as_float(u & 0xFFFF0000u), ay);
  }
  ax = ax > 0.f ? ax : expm1f(ax);
  ay = ay > 0.f ? ay : expm1f(ay);
  eb[(size_t)n * (D / 2) + lane] = (bfr(ay) << 16) | bfr(ax);
}

// ---------------- Kernel B (v6): MFMA GEMM, fast-tanh epilogue, partials -------------
__global__ __launch_bounds__(256) void k_fc5(
    const unsigned short* __restrict__ eb1, const unsigned short* __restrict__ eb2,
    const unsigned short* __restrict__ wb, const float* __restrict__ fcb,
    float* __restrict__ part, int N)
{
  const int path = blockIdx.y;
  const unsigned short* __restrict__ eb = path ? eb2 : eb1;
  const int lane = threadIdx.x & 63;
  const int wid  = threadIdx.x >> 6;
  const int wave = blockIdx.x * 4 + wid;
  const int r  = lane & 15;
  const int hi = lane >> 4;

  bf16x8 B[8][4];
#pragma unroll
  for (int jt = 0; jt < 8; ++jt)
#pragma unroll
    for (int kc = 0; kc < 4; ++kc)
      B[jt][kc] = *(const bf16x8*)(wb + (size_t)(jt * 16 + r) * D + kc * 32 + hi * 8);

  float bias[8];
#pragma unroll
  for (int jt = 0; jt < 8; ++jt) bias[jt] = fcb[jt * 16 + r];

  float wsum[8];
#pragma unroll
  for (int jt = 0; jt < 8; ++jt) wsum[jt] = 0.f;

  const int nstrips = (N + 15) / 16;
  for (int st = wave; st < nstrips; st += NWAVES) {
    const int n0 = st * 16;
    int na = n0 + r;
    if (na >= N) na = N - 1;  // clamp keeps loads in-bounds; masked in epilogue
    const unsigned short* arow = eb + (size_t)na * D + hi * 8;
    bf16x8 A[4];
#pragma unroll
    for (int kc = 0; kc < 4; ++kc) A[kc] = *(const bf16x8*)(arow + kc * 32);

    f32x4 acc[8];
#pragma unroll
    for (int jt = 0; jt < 8; ++jt) acc[jt] = (f32x4){0.f, 0.f, 0.f, 0.f};
#pragma unroll
    for (int kc = 0; kc < 4; ++kc)
#pragma unroll
      for (int jt = 0; jt < 8; ++jt)
        acc[jt] = __builtin_amdgcn_mfma_f32_16x16x32_bf16(A[kc], B[jt][kc], acc[jt], 0, 0, 0);

#pragma unroll
    for (int jt = 0; jt < 8; ++jt) {
      float s = 0.f;
#pragma unroll
      for (int q = 0; q < 4; ++q) {
        const int node = n0 + hi * 4 + q;
        const float t = fast_tanh(acc[jt][q] + bias[jt]);
        s += (node < N) ? t : 0.f;
      }
      s += __shfl_xor(s, 16, 64);
      s += __shfl_xor(s, 32, 64);
      wsum[jt] += s;
    }
  }

  __shared__ float sd[4][D];
  if (lane < 16) {
#pragma unroll
    for (int jt = 0; jt < 8; ++jt) sd[wid][jt * 16 + lane] = wsum[jt];
  }
  __syncthreads();
  const int t = threadIdx.x;
  if (t < D) {
    const float v = sd[0][t] + sd[1][t] + sd[2][t] + sd[3][t];
    part[((size_t)path * NB2 + blockIdx.x) * D + t] = v;
  }
}

// ---------------- Kernel C: reduce partials -> sps -> beta (1024 threads) -------------
// Thread layout: j = t&127, path = (t>>7)&1, chunk = t>>8 (4 chunks of NB2/4 rows).
__global__ __launch_bounds__(1024) void k_finish(
    const float* __restrict__ part, const float* __restrict__ att_inter,
    float* __restrict__ beta, float invN)
{
  const int t     = threadIdx.x;
  const int j     = t & 127;
  const int path  = (t >> 7) & 1;
  const int chunk = t >> 8;           // 0..3
  const int rows  = NB2 / 4;          // 98

  const float* __restrict__ p =
      part + (size_t)path * NB2 * D + (size_t)chunk * rows * D + j;
  float s = 0.f;
#pragma unroll 7
  for (int b = 0; b < rows; ++b) s += p[(size_t)b * D];

  __shared__ float sd[4][2][D];
  sd[chunk][path][j] = s;
  __syncthreads();

  if (t < 256) {
    const float tot = sd[0][path][j] + sd[1][path][j] + sd[2][path][j] + sd[3][path][j];
    float v = (tot * invN) * att_inter[j];
    v = wave_sum(v);                  // waves: 0=path0 j0-63, 1=path0 j64-127, 2/3=path1
    __shared__ float red[4];
    const int wid = t >> 6;
    if ((t & 63) == 0) red[wid] = v;
    __syncthreads();
    if (t == 0) {
      const float v0 = red[0] + red[1];
      const float v1 = red[2] + red[3];
      const float m = fmaxf(v0, v1);
      const float p0 = __expf(v0 - m), p1 = __expf(v1 - m);
      const float inv = 1.f / (p0 + p1);
      beta[0] = p0 * inv;
      beta[1] = p1 * inv;
    }
  }
}

// ---------------- Kernel D: out = b0*e1 + b1*e2 (bf16 sources, fp32 out) -------------
__global__ __launch_bounds__(256) void k_combine(
    const uint2* __restrict__ eb1v, const uint2* __restrict__ eb2v,
    const float* __restrict__ beta, float* __restrict__ outp, int total4)
{
  const float b0 = beta[0], b1 = beta[1];
  float4* out = (float4*)outp;
  int i = blockIdx.x * 256 + threadIdx.x;
  const int stride = gridDim.x * 256;
  for (; i < total4; i += stride) {
    const uint2 a = eb1v[i], b = eb2v[i];
    float4 o;
    o.x = b0 * __uint_as_float(a.x << 16)         + b1 * __uint_as_float(b.x << 16);
    o.y = b0 * __uint_as_float(a.x & 0xFFFF0000u) + b1 * __uint_as_float(b.x & 0xFFFF0000u);
    o.z = b0 * __uint_as_float(a.y << 16)         + b1 * __uint_as_float(b.y << 16);
    o.w = b0 * __uint_as_float(a.y & 0xFFFF0000u) + b1 * __uint_as_float(b.y & 0xFFFF0000u);
    out[i] = o;
  }
}

extern "C" void kernel_launch(void* const* d_in, const int* in_sizes, int n_in,
                              void* d_out, int out_size, void* d_ws, size_t ws_size,
                              hipStream_t stream) {
  const float* h_ref     = (const float*)d_in[0];
  const float* h1        = (const float*)d_in[1];
  const float* h2        = (const float*)d_in[2];
  const int*   nei1      = (const int*)d_in[3];
  const int*   nei2      = (const int*)d_in[4];
  const float* att1      = (const float*)d_in[5];
  const float* att2      = (const float*)d_in[6];
  const float* fcW       = (const float*)d_in[7];
  const float* fcb       = (const float*)d_in[8];
  const float* att_inter = (const float*)d_in[9];

  const int N  = in_sizes[0] / D;
  const int M  = in_sizes[1] / D;
  const int S1 = in_sizes[3] / N;
  const int S2 = in_sizes[4] / N;

  // No aliasing: intra paths run concurrently in one launch.
  unsigned short* hb1 = (unsigned short*)d_ws;                 // bf16 h1 [M*D]
  unsigned short* hb2 = hb1 + (size_t)M * D;                   // bf16 h2 [M*D]
  unsigned short* eb1 = hb2 + (size_t)M * D;                   // bf16 e1 [N*D]
  unsigned short* eb2 = eb1 + (size_t)N * D;                   // bf16 e2 [N*D]
  unsigned short* wb  = eb2 + (size_t)N * D;                   // bf16 W  [D*D]
  float* part = (float*)(wb + D * D);                          // [2][NB2][D]
  float* beta = part + (size_t)2 * NB2 * D;                    // 2 floats
  float* q1   = beta + 2;                                      // [N]
  float* q2   = q1 + N;                                        // [N]
  float* p1   = q2 + N;                                        // [M]
  float* p2   = p1 + M;                                        // [M]
  float* out  = (float*)d_out;

  unsigned* hb1u = (unsigned*)hb1;
  unsigned* hb2u = (unsigned*)hb2;
  unsigned* eb1u = (unsigned*)eb1;
  unsigned* eb2u = (unsigned*)eb2;

  const int rows = N + 2 * M + 64;
  k_proj<<<(rows + 3) / 4, 256, 0, stream>>>(h_ref, h1, h2, att1, att2, fcW, wb,
                                             q1, q2, p1, p2, hb1u, hb2u, N, M);

  const dim3 gA((N + 3) / 4, 2);
  if (S1 == 20 && S2 == 10)
    k_intra_dual<20, 10><<<gA, 256, 0, stream>>>(q1, p1, hb1u, nei1, eb1u,
                                                 q2, p2, hb2u, nei2, eb2u, N);
  else if (S1 == 10 && S2 == 20)
    k_intra_dual<10, 20><<<gA, 256, 0, stream>>>(q1, p1, hb1u, nei1, eb1u,
                                                 q2, p2, hb2u, nei2, eb2u, N);
  else if (S1 == 10 && S2 == 10)
    k_intra_dual<10, 10><<<gA, 256, 0, stream>>>(q1, p1, hb1u, nei1, eb1u,
                                                 q2, p2, hb2u, nei2, eb2u, N);
  else if (S1 == 20 && S2 == 20)
    k_intra_dual<20, 20><<<gA, 256, 0, stream>>>(q1, p1, hb1u, nei1, eb1u,
                                                 q2, p2, hb2u, nei2, eb2u, N);
  else {
    const dim3 g1((N + 3) / 4);
    k_intra3_gen<<<g1, 256, 0, stream>>>(q1, p1, hb1u, nei1, eb1u, N, S1);
    k_intra3_gen<<<g1, 256, 0, stream>>>(q2, p2, hb2u, nei2, eb2u, N, S2);
  }

  const dim3 gB(NB2, 2);
  k_fc5<<<gB, 256, 0, stream>>>(eb1, eb2, wb, fcb, part, N);

  k_finish<<<1, 1024, 0, stream>>>(part, att_inter, beta, 1.0f / (float)N);

  const int total4 = N * D / 4;
  int gD = (total4 + 255) / 256;
  if (gD > 2048) gD = 2048;
  k_combine<<<gD, 256, 0, stream>>>((const uint2*)eb1, (const uint2*)eb2, beta, out, total4);
}